// Round 2
// baseline (327.442 us; speedup 1.0000x reference)
//
#include <hip/hip_runtime.h>
#include <hip/hip_bf16.h>

// Problem constants (from reference): B=32, L=8192, C=128, K=7, F=128
#define BATCH 32
#define LEN   8192
#define CDIM  128
#define TAPS  7
#define FDIM  128
#define LOUT  (LEN - TAPS + 1)   // 8186
#define BM    128                // output rows per block
#define XROWS (BM + TAPS - 1)    // 134 rows of x per block

typedef __attribute__((ext_vector_type(8)))  short bf16x8;
typedef __attribute__((ext_vector_type(16))) float f32x16;

static __device__ __forceinline__ unsigned short bf16_rne(float f) {
    unsigned u = __float_as_uint(f);
    u += 0x7FFFu + ((u >> 16) & 1u);
    return (unsigned short)(u >> 16);
}
static __device__ __forceinline__ unsigned pack2(float a, float b) {
    return (unsigned)bf16_rne(a) | ((unsigned)bf16_rne(b) << 16);
}

// Pre-convert kernel W fp32 [K][C][F] -> bf16 transposed [K][F][C] in workspace.
__global__ void wconv_kernel(const float* __restrict__ w, ushort* __restrict__ wt) {
    int idx = blockIdx.x * 256 + threadIdx.x;         // 7*128*128 = 448*256 exactly
    int k = idx >> 14;
    int rem = idx & 16383;
    int f = rem >> 7;
    int c = rem & 127;
    wt[idx] = bf16_rne(w[(k << 14) + (c << 7) + f]);
}

// Main fused conv-as-GEMM kernel.
// Block: 256 threads (4 waves). Tile: 128 output rows x 128 F.
// LDS: Xs only (34 KB) -> up to 4 blocks/CU by LDS; VGPR cap targets 3.
// B fragments are read per-tap directly from global (224 KB total, L2-resident
// for all 2048 blocks) -> no Ws LDS, no in-loop barriers.
__global__ __launch_bounds__(256, 3)
void conv_gemm_kernel(const float* __restrict__ x, const ushort* __restrict__ wt,
                      float* __restrict__ out) {
    __shared__ __align__(16) ushort Xs[XROWS * CDIM];  // 34,304 B

    const int tid  = threadIdx.x;
    const int lane = tid & 63;
    const int wid  = tid >> 6;
    const int wm   = wid >> 1;       // wave row (0..1) -> 64 rows
    const int wn   = wid & 1;        // wave col (0..1) -> 64 f
    const int l31  = lane & 31;
    const int l5   = lane >> 5;

    const int bid  = blockIdx.x;
    const int b    = bid >> 6;       // 64 tiles per batch
    const int i0   = (bid & 63) * BM;

    const float* xb = x + (size_t)b * LEN * CDIM;

    // ---- Stage X window: fp32 global -> bf16 LDS, swizzled (col ^= row&15) ----
    // Fully unrolled so all HBM loads issue before any wait.
    #pragma unroll
    for (int it = 0; it < 9; ++it) {
        int q = it * 256 + tid;
        if (q < XROWS * 16) {
            int r   = q >> 4;
            int col = q & 15;
            int gi  = i0 + r;
            float4 v0, v1;
            if (gi < LEN) {
                const float4* p = (const float4*)(xb + (size_t)gi * CDIM + col * 8);
                v0 = p[0]; v1 = p[1];
            } else {
                v0 = make_float4(0.f, 0.f, 0.f, 0.f);
                v1 = v0;
            }
            int scol = col ^ (r & 15);
            uint4 pk;
            pk.x = pack2(v0.x, v0.y);
            pk.y = pack2(v0.z, v0.w);
            pk.z = pack2(v1.x, v1.y);
            pk.w = pack2(v1.z, v1.w);
            *(uint4*)&Xs[r * CDIM + scol * 8] = pk;
        }
    }

    __syncthreads();   // the ONLY barrier

    f32x16 acc[2][2] = {};

    const int f0 = (wn << 6) + l31;
    const int f1 = f0 + 32;

    #pragma unroll
    for (int t = 0; t < TAPS; ++t) {
        const ushort* wt_t = wt + t * (FDIM * CDIM);
        const int r0 = (wm << 6) + l31 + t;
        const int r1 = r0 + 32;

        // B fragments for this tap: direct global loads (L2-hot), no LDS.
        bf16x8 b0[8], b1[8];
        #pragma unroll
        for (int kk = 0; kk < 8; ++kk) {
            int off = (kk * 2 + l5) << 3;
            b0[kk] = *(const bf16x8*)(wt_t + f0 * CDIM + off);
            b1[kk] = *(const bf16x8*)(wt_t + f1 * CDIM + off);
        }

        #pragma unroll
        for (int kk = 0; kk < 8; ++kk) {
            int j = kk * 2 + l5;
            bf16x8 a0 = *(const bf16x8*)&Xs[r0 * CDIM + ((j ^ (r0 & 15)) << 3)];
            bf16x8 a1 = *(const bf16x8*)&Xs[r1 * CDIM + ((j ^ (r1 & 15)) << 3)];
            acc[0][0] = __builtin_amdgcn_mfma_f32_32x32x16_bf16(a0, b0[kk], acc[0][0], 0, 0, 0);
            acc[0][1] = __builtin_amdgcn_mfma_f32_32x32x16_bf16(a0, b1[kk], acc[0][1], 0, 0, 0);
            acc[1][0] = __builtin_amdgcn_mfma_f32_32x32x16_bf16(a1, b0[kk], acc[1][0], 0, 0, 0);
            acc[1][1] = __builtin_amdgcn_mfma_f32_32x32x16_bf16(a1, b1[kk], acc[1][1], 0, 0, 0);
        }
    }

    // ---- Epilogue: C/D layout col=lane&31, row=(reg&3)+8*(reg>>2)+4*(lane>>5) ----
    float* ob = out + (size_t)b * LOUT * FDIM;
    #pragma unroll
    for (int fm = 0; fm < 2; ++fm) {
        #pragma unroll
        for (int fn = 0; fn < 2; ++fn) {
            #pragma unroll
            for (int r = 0; r < 16; ++r) {
                int row = (wm << 6) + (fm << 5) + (r & 3) + ((r >> 2) << 3) + (l5 << 2);
                int i = i0 + row;
                if (i < LOUT) {
                    ob[(size_t)i * FDIM + (wn << 6) + (fn << 5) + l31] = acc[fm][fn][r];
                }
            }
        }
    }
}

extern "C" void kernel_launch(void* const* d_in, const int* in_sizes, int n_in,
                              void* d_out, int out_size, void* d_ws, size_t ws_size,
                              hipStream_t stream) {
    const float* x = (const float*)d_in[0];   // [32, 8192, 128, 1] fp32
    const float* w = (const float*)d_in[1];   // [7, 128, 128] fp32
    float* out = (float*)d_out;               // [32, 8186, 128, 1] fp32
    ushort* wt = (ushort*)d_ws;               // 7*128*128 bf16 = 229,376 B scratch

    wconv_kernel<<<448, 256, 0, stream>>>(w, wt);
    conv_gemm_kernel<<<BATCH * 64, 256, 0, stream>>>(x, wt, out);
}

// Round 3
// 272.735 us; speedup vs baseline: 1.2006x; 1.2006x over previous
//
#include <hip/hip_runtime.h>
#include <hip/hip_bf16.h>

// Problem constants (from reference): B=32, L=8192, C=128, K=7, F=128
#define BATCH 32
#define LEN   8192
#define CDIM  128
#define TAPS  7
#define FDIM  128
#define LOUT  (LEN - TAPS + 1)   // 8186
#define BM    128                // output rows per block
#define XROWS (BM + TAPS - 1)    // 134 rows of x per block
#define NCHUNK (TAPS * 2)        // 14 half-tap W chunks (F128 x C64 = 16 KB each)

typedef __attribute__((ext_vector_type(8)))  short bf16x8;
typedef __attribute__((ext_vector_type(16))) float f32x16;

static __device__ __forceinline__ unsigned short bf16_rne(float f) {
    unsigned u = __float_as_uint(f);
    u += 0x7FFFu + ((u >> 16) & 1u);
    return (unsigned short)(u >> 16);
}
static __device__ __forceinline__ unsigned pack2(float a, float b) {
    return (unsigned)bf16_rne(a) | ((unsigned)bf16_rne(b) << 16);
}

// Pre-convert kernel W fp32 [K][C][F] -> bf16 transposed [K][F][C] in workspace.
__global__ void wconv_kernel(const float* __restrict__ w, ushort* __restrict__ wt) {
    int idx = blockIdx.x * 256 + threadIdx.x;         // 7*128*128 = 448*256 exactly
    int k = idx >> 14;
    int rem = idx & 16383;
    int f = rem >> 7;
    int c = rem & 127;
    wt[idx] = bf16_rne(w[(k << 14) + (c << 7) + f]);
}

// Main fused conv-as-GEMM kernel.
// Block: 256 threads (4 waves). Tile: 128 output rows x 128 F.
// Xs: full X window in LDS (bf16, swizzled), loaded once.
// Ws: double-buffered 16 KB half-tap chunks, staged via global_load_lds with
// prefetch distance 1 -> the vmcnt(0) drain at each barrier waits on loads
// that already had a full compute phase to land (round-1's exposed-latency fix).
__global__ __launch_bounds__(256, 2)
void conv_gemm_kernel(const float* __restrict__ x, const ushort* __restrict__ wt,
                      float* __restrict__ out) {
    __shared__ __align__(16) ushort Xs[XROWS * CDIM];      // 34,304 B
    __shared__ __align__(16) ushort Ws[2][FDIM * 64];      // 2 x 16,384 B

    const int tid  = threadIdx.x;
    const int lane = tid & 63;
    const int wid  = tid >> 6;
    const int wm   = wid >> 1;       // wave row (0..1) -> 64 rows
    const int wn   = wid & 1;        // wave col (0..1) -> 64 f
    const int l31  = lane & 31;
    const int l5   = lane >> 5;

    const int bid  = blockIdx.x;
    const int b    = bid >> 6;       // 64 tiles per batch
    const int i0   = (bid & 63) * BM;

    const float* xb = x + (size_t)b * LEN * CDIM;

    // ---- W chunk staging: async direct-to-LDS, swizzled (slot j' holds src j'^(f&7)) ----
    // Chunk idx: tap t = idx>>1, C-half h = idx&1. 1024 16B slots; 4 per thread.
    auto stage_w = [&](int idx) {
        const ushort* wsrc = wt + (idx >> 1) * (FDIM * CDIM) + (idx & 1) * 64;
        ushort* wbuf = Ws[idx & 1];
        #pragma unroll
        for (int it = 0; it < 4; ++it) {
            int s  = it * 256 + tid;            // slot this lane fills
            int f  = s >> 3;
            int jp = s & 7;
            int j  = jp ^ (f & 7);              // source 16B chunk within the half-row
            const ushort* g = wsrc + f * CDIM + j * 8;
            // wave-uniform LDS base; HW adds lane*16
            ushort* l = &wbuf[(it * 256 + (tid & 192)) * 8];
            __builtin_amdgcn_global_load_lds(
                (const __attribute__((address_space(1))) void*)g,
                (__attribute__((address_space(3))) void*)l, 16, 0, 0);
        }
    };

    stage_w(0);   // prefetch chunk 0 (L2-hot after wconv)

    // ---- Stage X window: fp32 global -> bf16 LDS, swizzled (col ^= row&15) ----
    #pragma unroll
    for (int it = 0; it < 9; ++it) {
        int q = it * 256 + tid;
        if (q < XROWS * 16) {
            int r   = q >> 4;
            int col = q & 15;
            int gi  = i0 + r;
            float4 v0, v1;
            if (gi < LEN) {
                const float4* p = (const float4*)(xb + (size_t)gi * CDIM + col * 8);
                v0 = p[0]; v1 = p[1];
            } else {
                v0 = make_float4(0.f, 0.f, 0.f, 0.f);
                v1 = v0;
            }
            int scol = col ^ (r & 15);
            uint4 pk;
            pk.x = pack2(v0.x, v0.y);
            pk.y = pack2(v0.z, v0.w);
            pk.z = pack2(v1.x, v1.y);
            pk.w = pack2(v1.z, v1.w);
            *(uint4*)&Xs[r * CDIM + scol * 8] = pk;
        }
    }

    f32x16 acc[2][2] = {};

    const int f0 = (wn << 6) + l31;
    const int f1 = f0 + 32;
    const int swz0 = f0 & 7;
    const int swz1 = f1 & 7;   // == swz0, but keep explicit

    #pragma unroll
    for (int idx = 0; idx < NCHUNK; ++idx) {
        __syncthreads();              // chunk idx data landed; chunk idx-1 reads done
        if (idx + 1 < NCHUNK) stage_w(idx + 1);   // into other buffer, overlaps compute

        const int t = idx >> 1;
        const int h = idx & 1;
        const ushort* wb = Ws[idx & 1];
        const int r0 = (wm << 6) + l31 + t;
        const int r1 = r0 + 32;

        #pragma unroll
        for (int kk = 0; kk < 4; ++kk) {
            int jl = kk * 2 + l5;            // 0..7 within the C-half
            int jg = h * 8 + jl;             // 0..15 within the full row (for Xs)
            bf16x8 a0 = *(const bf16x8*)&Xs[r0 * CDIM + ((jg ^ (r0 & 15)) << 3)];
            bf16x8 a1 = *(const bf16x8*)&Xs[r1 * CDIM + ((jg ^ (r1 & 15)) << 3)];
            bf16x8 b0 = *(const bf16x8*)&wb[f0 * 64 + ((jl ^ swz0) << 3)];
            bf16x8 b1 = *(const bf16x8*)&wb[f1 * 64 + ((jl ^ swz1) << 3)];
            acc[0][0] = __builtin_amdgcn_mfma_f32_32x32x16_bf16(a0, b0, acc[0][0], 0, 0, 0);
            acc[0][1] = __builtin_amdgcn_mfma_f32_32x32x16_bf16(a0, b1, acc[0][1], 0, 0, 0);
            acc[1][0] = __builtin_amdgcn_mfma_f32_32x32x16_bf16(a1, b0, acc[1][0], 0, 0, 0);
            acc[1][1] = __builtin_amdgcn_mfma_f32_32x32x16_bf16(a1, b1, acc[1][1], 0, 0, 0);
        }
    }

    // ---- Epilogue: C/D layout col=lane&31, row=(reg&3)+8*(reg>>2)+4*(lane>>5) ----
    float* ob = out + (size_t)b * LOUT * FDIM;
    #pragma unroll
    for (int fm = 0; fm < 2; ++fm) {
        #pragma unroll
        for (int fn = 0; fn < 2; ++fn) {
            #pragma unroll
            for (int r = 0; r < 16; ++r) {
                int row = (wm << 6) + (fm << 5) + (r & 3) + ((r >> 2) << 3) + (l5 << 2);
                int i = i0 + row;
                if (i < LOUT) {
                    ob[(size_t)i * FDIM + (wn << 6) + (fn << 5) + l31] = acc[fm][fn][r];
                }
            }
        }
    }
}

extern "C" void kernel_launch(void* const* d_in, const int* in_sizes, int n_in,
                              void* d_out, int out_size, void* d_ws, size_t ws_size,
                              hipStream_t stream) {
    const float* x = (const float*)d_in[0];   // [32, 8192, 128, 1] fp32
    const float* w = (const float*)d_in[1];   // [7, 128, 128] fp32
    float* out = (float*)d_out;               // [32, 8186, 128, 1] fp32
    ushort* wt = (ushort*)d_ws;               // 7*128*128 bf16 = 229,376 B scratch

    wconv_kernel<<<448, 256, 0, stream>>>(w, wt);
    conv_gemm_kernel<<<BATCH * 64, 256, 0, stream>>>(x, wt, out);
}